// Round 2
// baseline (782.961 us; speedup 1.0000x reference)
//
#include <hip/hip_runtime.h>
#include <math.h>

// MemoryBank: B=64, C=1501, D=2048, fp32
//   out0 selected     [B,D]    = memory[cls_list]            (original memory)
//   out1 tmp_repeated [B,C,D]  = B copies of tmp_memory      (memory w/ rows cls_list <- x, last-write-wins)
//   out2 new_mem      [C,D]    = l2normalize(memory*(1-a) + tmp_memory*a)
//
// Dominant cost: 787 MB streaming write of out1. One block per class row.

#define ALPHA 0.01f
#define EPS_  1e-7f
#define B_    64
#define C_    1501
#define D_    2048
#define T_    256   // threads per block; D_/4 = 512 float4 = 2 per thread

// clang-native vector (HIP float4 is a struct; nontemporal builtin rejects it)
typedef float f32x4 __attribute__((ext_vector_type(4)));

__global__ __launch_bounds__(T_) void memorybank_kernel(
    const float* __restrict__ x,    // [B,D]
    const int*   __restrict__ cls,  // [B]
    const float* __restrict__ mem,  // [C,D]
    float*       __restrict__ out)  // [B*D + B*C*D + C*D]
{
    const int c   = blockIdx.x;
    const int tid = threadIdx.x;

    // --- which b's (if any) map to this row; winner = max b (last write wins) ---
    __shared__ unsigned long long s_mask;
    if (tid < 64) {
        int cb = cls[tid];
        unsigned long long m = __ballot(cb == c);
        if (tid == 0) s_mask = m;
    }
    __syncthreads();
    const unsigned long long mask = s_mask;
    const int winner = mask ? (63 - __clzll(mask)) : -1;

    // --- load memory row (2 float4 per thread, coalesced) ---
    const f32x4* mrow = (const f32x4*)(mem + (size_t)c * D_);
    f32x4 m0 = mrow[tid];
    f32x4 m1 = mrow[tid + T_];

    // --- tmp_memory row: x[winner] if scattered into, else memory row ---
    f32x4 t0 = m0, t1 = m1;
    if (winner >= 0) {
        const f32x4* xrow = (const f32x4*)(x + (size_t)winner * D_);
        t0 = xrow[tid];
        t1 = xrow[tid + T_];
    }

    // --- EMA row ---
    f32x4 n0 = m0 * (1.0f - ALPHA) + t0 * ALPHA;
    f32x4 n1 = m1 * (1.0f - ALPHA) + t1 * ALPHA;

    // --- row L2 norm: per-thread partial -> wave64 butterfly -> LDS across 4 waves ---
    float ss = n0.x*n0.x + n0.y*n0.y + n0.z*n0.z + n0.w*n0.w
             + n1.x*n1.x + n1.y*n1.y + n1.z*n1.z + n1.w*n1.w;
    #pragma unroll
    for (int off = 32; off > 0; off >>= 1)
        ss += __shfl_xor(ss, off, 64);
    __shared__ float s_part[T_ / 64];
    if ((tid & 63) == 0) s_part[tid >> 6] = ss;
    __syncthreads();
    const float total = s_part[0] + s_part[1] + s_part[2] + s_part[3];
    const float inv = 1.0f / (sqrtf(total) + EPS_);

    // --- output pointers (flat concatenation in return order) ---
    f32x4* out_sel = (f32x4*)out;                                       // [B][D]
    f32x4* out_rep = (f32x4*)(out + (size_t)B_ * D_);                   // [B][C][D]
    f32x4* out_new = (f32x4*)(out + (size_t)B_ * D_ + (size_t)B_ * C_ * D_); // [C][D]

    // --- new_mem row ---
    {
        f32x4 w0 = n0 * inv;
        f32x4 w1 = n1 * inv;
        const size_t base = (size_t)c * (D_ / 4);
        out_new[base + tid]      = w0;
        out_new[base + tid + T_] = w1;
    }

    // --- selected rows: every b with cls[b]==c gets the ORIGINAL memory row ---
    unsigned long long mm = mask;
    while (mm) {
        const int b = __ffsll(mm) - 1;
        mm &= mm - 1;
        const size_t base = (size_t)b * (D_ / 4);
        out_sel[base + tid]      = m0;
        out_sel[base + tid + T_] = m1;
    }

    // --- tmp_repeated: B copies of the tmp row (streaming, nontemporal) ---
    const size_t rowbase = (size_t)c * (D_ / 4) + tid;
    const size_t strideB = (size_t)C_ * (D_ / 4);
    #pragma unroll 4
    for (int b = 0; b < B_; ++b) {
        __builtin_nontemporal_store(t0, &out_rep[rowbase + (size_t)b * strideB]);
        __builtin_nontemporal_store(t1, &out_rep[rowbase + (size_t)b * strideB + T_]);
    }
}

extern "C" void kernel_launch(void* const* d_in, const int* in_sizes, int n_in,
                              void* d_out, int out_size, void* d_ws, size_t ws_size,
                              hipStream_t stream) {
    const float* x   = (const float*)d_in[0];
    const int*   cls = (const int*)  d_in[1];
    const float* mem = (const float*)d_in[2];
    float*       out = (float*)d_out;
    memorybank_kernel<<<C_, T_, 0, stream>>>(x, cls, mem, out);
}